// Round 12
// baseline (673.935 us; speedup 1.0000x reference)
//
#include <hip/hip_runtime.h>
#include <hip/hip_bf16.h>

// Problem constants
#define IN_CAPS  1152
#define NUM_CAPS 10
#define DIM_CAPS 16
#define B_TOT    256

// pre_kernel tiling (R4-proven shape: 768 blocks, 2 b/thread, ~62 us)
#define I_T     12
#define P_TILES (IN_CAPS / I_T)    // 96
#define B_BLK   32

#define WT_F    (IN_CAPS * DIM_CAPS * 2 * 16 * 4)

// persist kernel geometry: 256 blocks (one per b) x 512 threads.
// 32 groups x 16 n-lanes; each thread owns 36 i's: 22 in VGPRs + 14 in LDS.
#define GROUPS  32
#define K_PER   (IN_CAPS / GROUPS)   // 36
#define KR      22                   // i's held in registers (176 VGPRs)
#define KL      (K_PER - KR)         // 14 i's held in LDS

// dynamic LDS layout:
//   u_lds [32 g][14 k][10 n][2 uint4] = 143360 B
//   red   [8 w][16 n][17]             = 8704 B   (stride-17 rows)
//   Vl    [16 n][17]                  = 1088 B
#define ULDS_U4 (GROUPS * KL * NUM_CAPS * 2)
#define RED_F   (8 * 272)
#define VL_F    272
#define SMEM_BYTES (ULDS_U4 * 16 + RED_F * 4 + VL_F * 4)   // 153152

typedef float v2f __attribute__((ext_vector_type(2)));

__device__ __forceinline__ unsigned pack2_bf16(float a, float b) {
  __hip_bfloat162 h = __float22bfloat162_rn(make_float2(a, b));
  return *reinterpret_cast<unsigned*>(&h);
}
__device__ __forceinline__ v2f unpack2_bf16_v(unsigned w) {
  v2f r;
  r.x = __uint_as_float(w << 16);
  r.y = __uint_as_float(w & 0xffff0000u);
  return r;
}

// Transpose W[n][i][d][k8] -> Wt[i][d][h][n16][c4] (R3-proven).
__global__ __launch_bounds__(512) void transpose_kernel(
    const float* __restrict__ W, float* __restrict__ Wt) {
  const int i = blockIdx.x;
  const int t = threadIdx.x;
  const int n = t & 15;
  const int h = (t >> 4) & 1;
  const int d = t >> 5;
  const float4* Wf4 = (const float4*)W;
  float4* Wtf4 = (float4*)Wt;
  float4 v = make_float4(0.f, 0.f, 0.f, 0.f);
  if (n < NUM_CAPS) v = Wf4[((size_t)(n * IN_CAPS + i) * DIM_CAPS + d) * 2 + h];
  Wtf4[(size_t)i * 512 + d * 32 + h * 16 + n] = v;
}

// Compute u_hat once (b-shared W reads); write bf16 ubuf. (R10's pre, passed.)
__global__ __launch_bounds__(256) void pre_kernel(
    const float* __restrict__ x, const float* __restrict__ Wt,
    uint4* __restrict__ ubuf) {
  const int tid = threadIdx.x;
  const int n   = tid & 15;
  const int g   = tid >> 4;
  const int b0  = blockIdx.x * B_BLK + 2 * g;
  const int i0  = blockIdx.y * I_T;
  const bool active = (n < NUM_CAPS);

  const float4* __restrict__ Wtp = (const float4*)Wt;
  const float4* __restrict__ xp  = (const float4*)x;

  for (int i = i0; i < i0 + I_T; ++i) {
    float4 xa0 = xp[(size_t)(b0 * IN_CAPS + i) * 2];
    float4 xb0 = xp[(size_t)(b0 * IN_CAPS + i) * 2 + 1];
    float4 xa1 = xp[(size_t)((b0 + 1) * IN_CAPS + i) * 2];
    float4 xb1 = xp[(size_t)((b0 + 1) * IN_CAPS + i) * 2 + 1];

    const float4* wbase = Wtp + (size_t)i * 512 + n;

    float u0[DIM_CAPS], u1[DIM_CAPS];
#pragma unroll
    for (int d = 0; d < DIM_CAPS; ++d) {
      float4 wa = wbase[d * 32];
      float4 wb = wbase[d * 32 + 16];
      u0[d] = wa.x * xa0.x + wa.y * xa0.y + wa.z * xa0.z + wa.w * xa0.w
            + wb.x * xb0.x + wb.y * xb0.y + wb.z * xb0.z + wb.w * xb0.w;
      u1[d] = wa.x * xa1.x + wa.y * xa1.y + wa.z * xa1.z + wa.w * xa1.w
            + wb.x * xb1.x + wb.y * xb1.y + wb.z * xb1.z + wb.w * xb1.w;
    }

    if (active) {
      size_t ub0 = ((size_t)(b0 * IN_CAPS + i) * NUM_CAPS + n) * 2;
      size_t ub1 = ((size_t)((b0 + 1) * IN_CAPS + i) * NUM_CAPS + n) * 2;
      uint4 p0, p1;
      p0.x = pack2_bf16(u0[0], u0[1]);  p0.y = pack2_bf16(u0[2], u0[3]);
      p0.z = pack2_bf16(u0[4], u0[5]);  p0.w = pack2_bf16(u0[6], u0[7]);
      p1.x = pack2_bf16(u0[8], u0[9]);  p1.y = pack2_bf16(u0[10], u0[11]);
      p1.z = pack2_bf16(u0[12], u0[13]); p1.w = pack2_bf16(u0[14], u0[15]);
      ubuf[ub0] = p0; ubuf[ub0 + 1] = p1;
      p0.x = pack2_bf16(u1[0], u1[1]);  p0.y = pack2_bf16(u1[2], u1[3]);
      p0.z = pack2_bf16(u1[4], u1[5]);  p0.w = pack2_bf16(u1[6], u1[7]);
      p1.x = pack2_bf16(u1[8], u1[9]);  p1.y = pack2_bf16(u1[10], u1[11]);
      p1.z = pack2_bf16(u1[12], u1[13]); p1.w = pack2_bf16(u1[14], u1[15]);
      ubuf[ub1] = p0; ubuf[ub1 + 1] = p1;
    }
  }
}

// One softmax-weighted accumulate step for a single i.
__device__ __forceinline__ void route_step(
    uint4 w0, uint4 w1, const v2f V2[8], v2f s2[8], bool active) {
  v2f u0 = unpack2_bf16_v(w0.x), u1 = unpack2_bf16_v(w0.y);
  v2f u2 = unpack2_bf16_v(w0.z), u3 = unpack2_bf16_v(w0.w);
  v2f u4 = unpack2_bf16_v(w1.x), u5 = unpack2_bf16_v(w1.y);
  v2f u6 = unpack2_bf16_v(w1.z), u7 = unpack2_bf16_v(w1.w);
  v2f acc = u0 * V2[0] + u1 * V2[1] + u2 * V2[2] + u3 * V2[3]
          + u4 * V2[4] + u5 * V2[5] + u6 * V2[6] + u7 * V2[7];
  float bd = acc.x + acc.y;
  float e = active ? __expf(bd) : 0.f;
  float es = e;
#pragma unroll
  for (int m = 1; m < 16; m <<= 1) es += __shfl_xor(es, m, 16);
  float c = e / es;
  s2[0] += c * u0; s2[1] += c * u1; s2[2] += c * u2; s2[3] += c * u3;
  s2[4] += c * u4; s2[5] += c * u5; s2[6] += c * u6; s2[7] += c * u7;
}

// Block-local s-reduction + squash + V-update (or output). All in LDS.
__device__ __forceinline__ void reduce_pass(
    v2f s2[8], float* red, float* Vl, float* __restrict__ out, int b,
    int tid, int n, int w, bool final_pass) {
  // sum the 4 16-lane groups within each wave
#pragma unroll
  for (int j = 0; j < 8; ++j) {
    float x = s2[j].x, y = s2[j].y;
    x += __shfl_xor(x, 16); y += __shfl_xor(y, 16);
    x += __shfl_xor(x, 32); y += __shfl_xor(y, 32);
    s2[j].x = x; s2[j].y = y;
  }
  if ((tid & 63) < 16) {
    float* rp = red + w * 272 + n * 17;
#pragma unroll
    for (int j = 0; j < 8; ++j) { rp[2 * j] = s2[j].x; rp[2 * j + 1] = s2[j].y; }
  }
  __syncthreads();
  if (tid < 160) {
    float s = 0.f;
#pragma unroll
    for (int ww = 0; ww < 8; ++ww)
      s += red[ww * 272 + (tid >> 4) * 17 + (tid & 15)];
    float sq = s * s;
#pragma unroll
    for (int m = 1; m < 16; m <<= 1) sq += __shfl_xor(sq, m, 16);  // over d
    float norm = sqrtf(sq);
    float v = s * (sq / (1.f + sq)) / (norm + 1e-8f);
    if (final_pass) out[b * 160 + tid] = v;
    else Vl[(tid >> 4) * 17 + (tid & 15)] += v;
  }
  __syncthreads();
}

// Persistent per-b routing: load u_hat[b] once into regs+LDS (fusing pass-0's
// c=0.1 sum), then passes 1..3 entirely on-chip. No grid sync needed.
__global__ __launch_bounds__(512, 2) void persist_kernel(
    const uint4* __restrict__ ubuf, float* __restrict__ out) {
  extern __shared__ char smem[];
  uint4* u_lds = (uint4*)smem;
  float* red   = (float*)(smem + (size_t)ULDS_U4 * 16);
  float* Vl    = red + RED_F;

  const int tid = threadIdx.x;
  const int n   = tid & 15;
  const int g   = tid >> 4;   // 0..31
  const int w   = tid >> 6;   // wave 0..7
  const int b   = blockIdx.x;
  const bool active = (n < NUM_CAPS);
  const int nn = active ? n : 0;

  if (tid < VL_F) Vl[tid] = 0.f;

  // ---- load u; accumulate pass-0 s = 0.1 * sum_i u ----
  uint4 ua[KR], ub_[KR];
  v2f s2[8];
#pragma unroll
  for (int j = 0; j < 8; ++j) s2[j] = (v2f)(0.f);
  const uint4* ubase =
      ubuf + ((size_t)(b * IN_CAPS + g * K_PER) * NUM_CAPS + nn) * 2;
#pragma unroll
  for (int k = 0; k < KR; ++k) {
    uint4 w0 = ubase[(size_t)k * (NUM_CAPS * 2)];
    uint4 w1 = ubase[(size_t)k * (NUM_CAPS * 2) + 1];
    ua[k] = w0; ub_[k] = w1;
    s2[0] += unpack2_bf16_v(w0.x); s2[1] += unpack2_bf16_v(w0.y);
    s2[2] += unpack2_bf16_v(w0.z); s2[3] += unpack2_bf16_v(w0.w);
    s2[4] += unpack2_bf16_v(w1.x); s2[5] += unpack2_bf16_v(w1.y);
    s2[6] += unpack2_bf16_v(w1.z); s2[7] += unpack2_bf16_v(w1.w);
  }
#pragma unroll
  for (int k = KR; k < K_PER; ++k) {
    uint4 w0 = ubase[(size_t)k * (NUM_CAPS * 2)];
    uint4 w1 = ubase[(size_t)k * (NUM_CAPS * 2) + 1];
    if (active) {
      int idx = ((g * KL + (k - KR)) * NUM_CAPS + n) * 2;
      u_lds[idx] = w0; u_lds[idx + 1] = w1;
    }
    s2[0] += unpack2_bf16_v(w0.x); s2[1] += unpack2_bf16_v(w0.y);
    s2[2] += unpack2_bf16_v(w0.z); s2[3] += unpack2_bf16_v(w0.w);
    s2[4] += unpack2_bf16_v(w1.x); s2[5] += unpack2_bf16_v(w1.y);
    s2[6] += unpack2_bf16_v(w1.z); s2[7] += unpack2_bf16_v(w1.w);
  }
  if (!active) {
#pragma unroll
    for (int j = 0; j < 8; ++j) s2[j] = (v2f)(0.f);
  }
#pragma unroll
  for (int j = 0; j < 8; ++j) s2[j] *= 0.1f;

  // pass 0: reduce -> v1 -> V (also covers the u_lds-store sync)
  reduce_pass(s2, red, Vl, out, b, tid, n, w, false);

  v2f V2[8];
#pragma unroll
  for (int j = 0; j < 8; ++j) {
    V2[j].x = Vl[nn * 17 + 2 * j];
    V2[j].y = Vl[nn * 17 + 2 * j + 1];
  }

  // ---- passes 1..3 from regs + LDS ----
  for (int pass = 1; pass < 4; ++pass) {
#pragma unroll
    for (int j = 0; j < 8; ++j) s2[j] = (v2f)(0.f);
#pragma unroll
    for (int k = 0; k < KR; ++k) route_step(ua[k], ub_[k], V2, s2, active);
#pragma unroll
    for (int k = 0; k < KL; ++k) {
      int idx = ((g * KL + k) * NUM_CAPS + nn) * 2;
      uint4 w0 = u_lds[idx];
      uint4 w1 = u_lds[idx + 1];
      route_step(w0, w1, V2, s2, active);
    }
    reduce_pass(s2, red, Vl, out, b, tid, n, w, pass == 3);
    if (pass < 3) {
#pragma unroll
      for (int j = 0; j < 8; ++j) {
        V2[j].x = Vl[nn * 17 + 2 * j];
        V2[j].y = Vl[nn * 17 + 2 * j + 1];
      }
    }
  }
}

extern "C" void kernel_launch(void* const* d_in, const int* in_sizes, int n_in,
                              void* d_out, int out_size, void* d_ws, size_t ws_size,
                              hipStream_t stream) {
  const float* x = (const float*)d_in[0];  // [256,1152,8]
  const float* W = (const float*)d_in[1];  // [1,10,1152,16,8]
  float* out  = (float*)d_out;             // [256,10,16]
  float* Wt   = (float*)d_ws;
  uint4* ubuf = (uint4*)((char*)d_ws + (size_t)WT_F * sizeof(float));

  // allow 153 KB dynamic LDS (160 KB/CU on gfx950); host-side, capture-safe
  hipFuncSetAttribute((const void*)persist_kernel,
                      hipFuncAttributeMaxDynamicSharedMemorySize, SMEM_BYTES);

  transpose_kernel<<<IN_CAPS, 512, 0, stream>>>(W, Wt);
  pre_kernel<<<dim3(B_TOT / B_BLK, P_TILES), 256, 0, stream>>>(x, Wt, ubuf);
  persist_kernel<<<B_TOT, 512, SMEM_BYTES, stream>>>(ubuf, out);
}

// Round 13
// 672.154 us; speedup vs baseline: 1.0027x; 1.0027x over previous
//
#include <hip/hip_runtime.h>
#include <hip/hip_bf16.h>

// Problem constants
#define IN_CAPS  1152
#define NUM_CAPS 10
#define DIM_CAPS 16
#define B_TOT    256

// pre_kernel tiling (R4-proven shape: 768 blocks, 2 b/thread, ~62 us)
#define I_T     12
#define P_TILES (IN_CAPS / I_T)    // 96
#define B_BLK   32

#define WT_F    (IN_CAPS * DIM_CAPS * 2 * 16 * 4)

// persist kernel geometry: 256 blocks (one per b) x 512 threads.
// 32 groups x 16 n-lanes; each thread owns 36 i's: 22 in VGPRs + 14 in LDS.
// R11 lesson: __launch_bounds__ 2nd arg acts as min-BLOCKS/CU on this
// toolchain (R11's (512,2) forced a 128-VGPR cap -> full spill, 704 MB fetch).
// (512,1) -> 2 waves/SIMD -> 256-VGPR cap; u-storage needs ~235.
#define GROUPS  32
#define K_PER   (IN_CAPS / GROUPS)   // 36
#define KR      22                   // i's held in registers (176 VGPRs)
#define KL      (K_PER - KR)         // 14 i's held in LDS

// dynamic LDS layout:
//   u_lds [32 g][14 k][10 n][2 uint4] = 143360 B
//   red   [8 w][16 n][17]             = 8704 B   (stride-17 rows)
//   Vl    [16 n][17]                  = 1088 B
#define ULDS_U4 (GROUPS * KL * NUM_CAPS * 2)
#define RED_F   (8 * 272)
#define VL_F    272
#define SMEM_BYTES (ULDS_U4 * 16 + RED_F * 4 + VL_F * 4)   // 153152

typedef float v2f __attribute__((ext_vector_type(2)));

__device__ __forceinline__ unsigned pack2_bf16(float a, float b) {
  __hip_bfloat162 h = __float22bfloat162_rn(make_float2(a, b));
  return *reinterpret_cast<unsigned*>(&h);
}
__device__ __forceinline__ v2f unpack2_bf16_v(unsigned w) {
  v2f r;
  r.x = __uint_as_float(w << 16);
  r.y = __uint_as_float(w & 0xffff0000u);
  return r;
}

// Transpose W[n][i][d][k8] -> Wt[i][d][h][n16][c4] (R3-proven).
__global__ __launch_bounds__(512) void transpose_kernel(
    const float* __restrict__ W, float* __restrict__ Wt) {
  const int i = blockIdx.x;
  const int t = threadIdx.x;
  const int n = t & 15;
  const int h = (t >> 4) & 1;
  const int d = t >> 5;
  const float4* Wf4 = (const float4*)W;
  float4* Wtf4 = (float4*)Wt;
  float4 v = make_float4(0.f, 0.f, 0.f, 0.f);
  if (n < NUM_CAPS) v = Wf4[((size_t)(n * IN_CAPS + i) * DIM_CAPS + d) * 2 + h];
  Wtf4[(size_t)i * 512 + d * 32 + h * 16 + n] = v;
}

// Compute u_hat once (b-shared W reads); write bf16 ubuf. (R10's pre, passed.)
__global__ __launch_bounds__(256) void pre_kernel(
    const float* __restrict__ x, const float* __restrict__ Wt,
    uint4* __restrict__ ubuf) {
  const int tid = threadIdx.x;
  const int n   = tid & 15;
  const int g   = tid >> 4;
  const int b0  = blockIdx.x * B_BLK + 2 * g;
  const int i0  = blockIdx.y * I_T;
  const bool active = (n < NUM_CAPS);

  const float4* __restrict__ Wtp = (const float4*)Wt;
  const float4* __restrict__ xp  = (const float4*)x;

  for (int i = i0; i < i0 + I_T; ++i) {
    float4 xa0 = xp[(size_t)(b0 * IN_CAPS + i) * 2];
    float4 xb0 = xp[(size_t)(b0 * IN_CAPS + i) * 2 + 1];
    float4 xa1 = xp[(size_t)((b0 + 1) * IN_CAPS + i) * 2];
    float4 xb1 = xp[(size_t)((b0 + 1) * IN_CAPS + i) * 2 + 1];

    const float4* wbase = Wtp + (size_t)i * 512 + n;

    float u0[DIM_CAPS], u1[DIM_CAPS];
#pragma unroll
    for (int d = 0; d < DIM_CAPS; ++d) {
      float4 wa = wbase[d * 32];
      float4 wb = wbase[d * 32 + 16];
      u0[d] = wa.x * xa0.x + wa.y * xa0.y + wa.z * xa0.z + wa.w * xa0.w
            + wb.x * xb0.x + wb.y * xb0.y + wb.z * xb0.z + wb.w * xb0.w;
      u1[d] = wa.x * xa1.x + wa.y * xa1.y + wa.z * xa1.z + wa.w * xa1.w
            + wb.x * xb1.x + wb.y * xb1.y + wb.z * xb1.z + wb.w * xb1.w;
    }

    if (active) {
      size_t ub0 = ((size_t)(b0 * IN_CAPS + i) * NUM_CAPS + n) * 2;
      size_t ub1 = ((size_t)((b0 + 1) * IN_CAPS + i) * NUM_CAPS + n) * 2;
      uint4 p0, p1;
      p0.x = pack2_bf16(u0[0], u0[1]);  p0.y = pack2_bf16(u0[2], u0[3]);
      p0.z = pack2_bf16(u0[4], u0[5]);  p0.w = pack2_bf16(u0[6], u0[7]);
      p1.x = pack2_bf16(u0[8], u0[9]);  p1.y = pack2_bf16(u0[10], u0[11]);
      p1.z = pack2_bf16(u0[12], u0[13]); p1.w = pack2_bf16(u0[14], u0[15]);
      ubuf[ub0] = p0; ubuf[ub0 + 1] = p1;
      p0.x = pack2_bf16(u1[0], u1[1]);  p0.y = pack2_bf16(u1[2], u1[3]);
      p0.z = pack2_bf16(u1[4], u1[5]);  p0.w = pack2_bf16(u1[6], u1[7]);
      p1.x = pack2_bf16(u1[8], u1[9]);  p1.y = pack2_bf16(u1[10], u1[11]);
      p1.z = pack2_bf16(u1[12], u1[13]); p1.w = pack2_bf16(u1[14], u1[15]);
      ubuf[ub1] = p0; ubuf[ub1 + 1] = p1;
    }
  }
}

// One softmax-weighted accumulate step for a single i.
__device__ __forceinline__ void route_step(
    uint4 w0, uint4 w1, const v2f V2[8], v2f s2[8], bool active) {
  v2f u0 = unpack2_bf16_v(w0.x), u1 = unpack2_bf16_v(w0.y);
  v2f u2 = unpack2_bf16_v(w0.z), u3 = unpack2_bf16_v(w0.w);
  v2f u4 = unpack2_bf16_v(w1.x), u5 = unpack2_bf16_v(w1.y);
  v2f u6 = unpack2_bf16_v(w1.z), u7 = unpack2_bf16_v(w1.w);
  v2f acc = u0 * V2[0] + u1 * V2[1] + u2 * V2[2] + u3 * V2[3]
          + u4 * V2[4] + u5 * V2[5] + u6 * V2[6] + u7 * V2[7];
  float bd = acc.x + acc.y;
  float e = active ? __expf(bd) : 0.f;
  float es = e;
#pragma unroll
  for (int m = 1; m < 16; m <<= 1) es += __shfl_xor(es, m, 16);
  float c = e / es;
  s2[0] += c * u0; s2[1] += c * u1; s2[2] += c * u2; s2[3] += c * u3;
  s2[4] += c * u4; s2[5] += c * u5; s2[6] += c * u6; s2[7] += c * u7;
}

// Block-local s-reduction + squash + V-update (or output). All in LDS.
__device__ __forceinline__ void reduce_pass(
    v2f s2[8], float* red, float* Vl, float* __restrict__ out, int b,
    int tid, int n, int w, bool final_pass) {
  // sum the 4 16-lane groups within each wave
#pragma unroll
  for (int j = 0; j < 8; ++j) {
    float x = s2[j].x, y = s2[j].y;
    x += __shfl_xor(x, 16); y += __shfl_xor(y, 16);
    x += __shfl_xor(x, 32); y += __shfl_xor(y, 32);
    s2[j].x = x; s2[j].y = y;
  }
  if ((tid & 63) < 16) {
    float* rp = red + w * 272 + n * 17;
#pragma unroll
    for (int j = 0; j < 8; ++j) { rp[2 * j] = s2[j].x; rp[2 * j + 1] = s2[j].y; }
  }
  __syncthreads();
  if (tid < 160) {
    float s = 0.f;
#pragma unroll
    for (int ww = 0; ww < 8; ++ww)
      s += red[ww * 272 + (tid >> 4) * 17 + (tid & 15)];
    float sq = s * s;
#pragma unroll
    for (int m = 1; m < 16; m <<= 1) sq += __shfl_xor(sq, m, 16);  // over d
    float norm = sqrtf(sq);
    float v = s * (sq / (1.f + sq)) / (norm + 1e-8f);
    if (final_pass) out[b * 160 + tid] = v;
    else Vl[(tid >> 4) * 17 + (tid & 15)] += v;
  }
  __syncthreads();
}

// Persistent per-b routing: load u_hat[b] once into regs+LDS (fusing pass-0's
// c=0.1 sum), then passes 1..3 entirely on-chip. No grid sync needed.
// launch_bounds(512, 1): 1 block/CU -> 2 waves/SIMD -> 256-VGPR cap (no spill).
__global__ __launch_bounds__(512, 1) void persist_kernel(
    const uint4* __restrict__ ubuf, float* __restrict__ out) {
  extern __shared__ char smem[];
  uint4* u_lds = (uint4*)smem;
  float* red   = (float*)(smem + (size_t)ULDS_U4 * 16);
  float* Vl    = red + RED_F;

  const int tid = threadIdx.x;
  const int n   = tid & 15;
  const int g   = tid >> 4;   // 0..31
  const int w   = tid >> 6;   // wave 0..7
  const int b   = blockIdx.x;
  const bool active = (n < NUM_CAPS);
  const int nn = active ? n : 0;

  if (tid < VL_F) Vl[tid] = 0.f;

  // ---- load u; accumulate pass-0 s = 0.1 * sum_i u ----
  uint4 ua[KR], ub_[KR];
  v2f s2[8];
#pragma unroll
  for (int j = 0; j < 8; ++j) s2[j] = (v2f)(0.f);
  const uint4* ubase =
      ubuf + ((size_t)(b * IN_CAPS + g * K_PER) * NUM_CAPS + nn) * 2;
#pragma unroll
  for (int k = 0; k < KR; ++k) {
    uint4 w0 = ubase[(size_t)k * (NUM_CAPS * 2)];
    uint4 w1 = ubase[(size_t)k * (NUM_CAPS * 2) + 1];
    ua[k] = w0; ub_[k] = w1;
    s2[0] += unpack2_bf16_v(w0.x); s2[1] += unpack2_bf16_v(w0.y);
    s2[2] += unpack2_bf16_v(w0.z); s2[3] += unpack2_bf16_v(w0.w);
    s2[4] += unpack2_bf16_v(w1.x); s2[5] += unpack2_bf16_v(w1.y);
    s2[6] += unpack2_bf16_v(w1.z); s2[7] += unpack2_bf16_v(w1.w);
  }
#pragma unroll
  for (int k = KR; k < K_PER; ++k) {
    uint4 w0 = ubase[(size_t)k * (NUM_CAPS * 2)];
    uint4 w1 = ubase[(size_t)k * (NUM_CAPS * 2) + 1];
    if (active) {
      int idx = ((g * KL + (k - KR)) * NUM_CAPS + n) * 2;
      u_lds[idx] = w0; u_lds[idx + 1] = w1;
    }
    s2[0] += unpack2_bf16_v(w0.x); s2[1] += unpack2_bf16_v(w0.y);
    s2[2] += unpack2_bf16_v(w0.z); s2[3] += unpack2_bf16_v(w0.w);
    s2[4] += unpack2_bf16_v(w1.x); s2[5] += unpack2_bf16_v(w1.y);
    s2[6] += unpack2_bf16_v(w1.z); s2[7] += unpack2_bf16_v(w1.w);
  }
  if (!active) {
#pragma unroll
    for (int j = 0; j < 8; ++j) s2[j] = (v2f)(0.f);
  }
#pragma unroll
  for (int j = 0; j < 8; ++j) s2[j] *= 0.1f;

  // pass 0: reduce -> v1 -> V (also covers the u_lds-store sync)
  reduce_pass(s2, red, Vl, out, b, tid, n, w, false);

  v2f V2[8];
#pragma unroll
  for (int j = 0; j < 8; ++j) {
    V2[j].x = Vl[nn * 17 + 2 * j];
    V2[j].y = Vl[nn * 17 + 2 * j + 1];
  }

  // ---- passes 1..3 from regs + LDS ----
  for (int pass = 1; pass < 4; ++pass) {
#pragma unroll
    for (int j = 0; j < 8; ++j) s2[j] = (v2f)(0.f);
#pragma unroll
    for (int k = 0; k < KR; ++k) route_step(ua[k], ub_[k], V2, s2, active);
#pragma unroll
    for (int k = 0; k < KL; ++k) {
      int idx = ((g * KL + k) * NUM_CAPS + nn) * 2;
      uint4 w0 = u_lds[idx];
      uint4 w1 = u_lds[idx + 1];
      route_step(w0, w1, V2, s2, active);
    }
    reduce_pass(s2, red, Vl, out, b, tid, n, w, pass == 3);
    if (pass < 3) {
#pragma unroll
      for (int j = 0; j < 8; ++j) {
        V2[j].x = Vl[nn * 17 + 2 * j];
        V2[j].y = Vl[nn * 17 + 2 * j + 1];
      }
    }
  }
}

extern "C" void kernel_launch(void* const* d_in, const int* in_sizes, int n_in,
                              void* d_out, int out_size, void* d_ws, size_t ws_size,
                              hipStream_t stream) {
  const float* x = (const float*)d_in[0];  // [256,1152,8]
  const float* W = (const float*)d_in[1];  // [1,10,1152,16,8]
  float* out  = (float*)d_out;             // [256,10,16]
  float* Wt   = (float*)d_ws;
  uint4* ubuf = (uint4*)((char*)d_ws + (size_t)WT_F * sizeof(float));

  // allow 153 KB dynamic LDS (160 KB/CU on gfx950); host-side, capture-safe
  hipFuncSetAttribute((const void*)persist_kernel,
                      hipFuncAttributeMaxDynamicSharedMemorySize, SMEM_BYTES);

  transpose_kernel<<<IN_CAPS, 512, 0, stream>>>(W, Wt);
  pre_kernel<<<dim3(B_TOT / B_BLK, P_TILES), 256, 0, stream>>>(x, Wt, ubuf);
  persist_kernel<<<B_TOT, 512, SMEM_BYTES, stream>>>(ubuf, out);
}